// Round 6
// baseline (52.246 us; speedup 1.0000x reference)
//
#include <hip/hip_runtime.h>
#include <string.h>

// Fused ConvNet on MFMA: conv7x7 s3 (3->4) -> ^2 -> FC 324->64 -> ^2 -> FC 64->10
// Round 6: window-major LDS layout for x. Each conv A-fragment is ONE aligned
// ds_read_b128 (was 4x ds_read_b32 + 4x alignbit). Window extraction happens at
// staging: 192 threads each own one (sample,ci,row), load the full 32-float row,
// pack to fp16, write 9 overlapping 8-half windows (2.25x LDS duplication).
// Conv weights single fp16 (fc1 keeps hi/lo split). Single-buffered X, 16 samples
// per 256-thr block, LDS 39168 B -> 4 blocks/CU.

typedef _Float16 f16;
typedef f16 f16x8 __attribute__((ext_vector_type(8)));
typedef __fp16 fp16x2 __attribute__((ext_vector_type(2)));
typedef float f32x4 __attribute__((ext_vector_type(4)));

#define YS_B   27648                   // byte offset of YS region
#define LDS_B  (27648 + 11520)         // WIN[2][6912]h + YS[16][360]h

__device__ __forceinline__ unsigned pack_rtz(float a, float b) {
    fp16x2 h = __builtin_amdgcn_cvt_pkrtz(a, b);
    unsigned u; memcpy(&u, &h, 4); return u;
}

// pack one row (8 float4 = 32 cols) and write its 9 windows of 8 halves
__device__ __forceinline__ void write_windows(f16* wptr, const float4 ldv[8]) {
    unsigned h[16];
#pragma unroll
    for (int i = 0; i < 8; ++i) {
        h[2*i]   = pack_rtz(ldv[i].x, ldv[i].y);
        h[2*i+1] = pack_rtz(ldv[i].z, ldv[i].w);
    }
#pragma unroll
    for (int ow = 0; ow < 9; ow += 2) {          // 3*ow even: direct
        int d = (3 * ow) >> 1;
        uint4 v; v.x = h[d]; v.y = h[d+1]; v.z = h[d+2]; v.w = h[d+3];
        *reinterpret_cast<uint4*>(wptr + ow * 8) = v;
    }
#pragma unroll
    for (int ow = 1; ow < 9; ow += 2) {          // 3*ow odd: shift by one half
        int d = (3 * ow) >> 1;
        uint4 v;
        v.x = __builtin_amdgcn_alignbit(h[d+1], h[d],   16);
        v.y = __builtin_amdgcn_alignbit(h[d+2], h[d+1], 16);
        v.z = __builtin_amdgcn_alignbit(h[d+3], h[d+2], 16);
        v.w = __builtin_amdgcn_alignbit(h[d+4], h[d+3], 16);
        *reinterpret_cast<uint4*>(wptr + ow * 8) = v;
    }
}

// ---------------- weight prep: fp16 (hi/lo) layouts in ws ----------------
// w1t: [2][64][352] f16  (fc1, k = oc*81+p, zero-padded k>=324)
// wct: [2][16][192] f16  (conv, row = oc (>=4 zero), k = seg*8+kw, kw<7 real)
__global__ void prep_weights(const float* __restrict__ cw, const float* __restrict__ fc1w,
                             f16* __restrict__ w1t, f16* __restrict__ wct) {
    int idx = blockIdx.x * 256 + threadIdx.x;
    if (idx < 45056) {
        int part = idx / 22528;
        int rem  = idx % 22528;
        int n = rem / 352, k = rem % 352;
        float v = (k < 324) ? fc1w[n * 324 + k] : 0.f;
        f16 hi = (f16)v;
        w1t[idx] = (part == 0) ? hi : (f16)(v - (float)hi);
    } else if (idx < 45056 + 6144) {
        int j = idx - 45056;
        int part = j / 3072;
        int rem  = j % 3072;
        int oc = rem / 192, k = rem % 192;
        int seg = k >> 3, kw = k & 7;
        float v = 0.f;
        if (oc < 4 && seg < 21 && kw < 7) {
            int ci = seg / 7, kh = seg % 7;
            v = cw[((oc * 3 + ci) * 7 + kh) * 7 + kw];
        }
        f16 hi = (f16)v;
        wct[j] = (part == 0) ? hi : (f16)(v - (float)hi);
    }
}

__global__ __launch_bounds__(256, 4) void convnet_mfma(
    const float* __restrict__ x,
    const f16*  __restrict__ w1t,     // [2][64][352]
    const f16*  __restrict__ wct,     // [2][16][192] (part 0 used)
    const float* __restrict__ fc1b,
    const float* __restrict__ fc2w,
    const float* __restrict__ fc2b,
    float* __restrict__ out)
{
    __shared__ unsigned char lds[LDS_B];
    f16* WINH = (f16*)lds;                         // [2 samples][3][32][9][8] halves
    f16* YS   = (f16*)(lds + YS_B);                // [16][360] halves
    float* HSQ = (float*)lds;                      // overlay (post-conv)

    const int t    = threadIdx.x;
    const int lane = t & 63;
    const int w    = t >> 6;
    const int g    = lane >> 4;
    const int lr   = lane & 15;
    const size_t base_s = (size_t)blockIdx.x * 16;

    // conv W fragments (single fp16): lane holds col=lr, k = st*32+g*8..+7
    f16x8 wcf[6];
#pragma unroll
    for (int st = 0; st < 6; ++st)
        wcf[st] = *(const f16x8*)(wct + lr * 192 + st * 32 + g * 8);

    // seg byte offsets (seg = st*4+g, clamped to 20; pad segs have zero weights)
    int seg2off[6];
#pragma unroll
    for (int st = 0; st < 6; ++st) {
        int seg  = st * 4 + g;
        int segc = seg > 20 ? 20 : seg;
        int ci   = segc >= 14 ? 2 : (segc >= 7 ? 1 : 0);
        int kh   = segc - ci * 7;
        seg2off[st] = ci * 4608 + kh * 144;        // bytes: ci*(32*9*16) + kh*(9*16)
    }
    // tiles per wave: w0{0,4,8} w1{1,5,9} w2{2,6} w3{3,7,10}  (w2 light: it stages)
    const int ntiles = (w == 2) ? 2 : 3;
    int rowbase[3], coff[3][4];
#pragma unroll
    for (int ti = 0; ti < 3; ++ti) {
        int tile = w + ti * 4;
        if (w == 3 && ti == 2) tile = 10;
        int grow = tile * 16 + lr;
        int growc = grow > 161 ? 161 : grow;
        int sp  = growc >= 81;
        int p   = growc - (sp ? 81 : 0);
        int oh  = (p * 57) >> 9;
        int ow  = p - oh * 9;
        rowbase[ti] = sp * 13824 + oh * 432 + ow * 16;   // bytes
#pragma unroll
        for (int r = 0; r < 4; ++r) {
            int gr = tile * 16 + g * 4 + r;
            if (ti < ntiles && gr < 162) {
                int sp2 = gr >= 81;
                int p2  = gr - (sp2 ? 81 : 0);
                coff[ti][r] = sp2 * 360 + lr * 81 + p2;
            } else coff[ti][r] = -1;
        }
    }

    // staging identity: 192 threads own (sample, ci, row)
    const bool stg = t < 192;
    const int ssp  = (t >= 96) ? 1 : 0;
    const int srem = t - ssp * 96;
    const int sci  = srem >> 5;
    const int srow = srem & 31;
    const int goff = sci * 1024 + srow * 32;
    f16* wptr = WINH + ssp * 6912 + sci * 2304 + srow * 72;

    // prologue: load + write pair 0, zero YS
    float4 ldv[8];
    if (stg) {
        const float* gp = x + (base_s + ssp) * 3072 + goff;
#pragma unroll
        for (int i = 0; i < 8; ++i) ldv[i] = *(const float4*)(gp + 4 * i);
    }
#pragma unroll
    for (int i = 0; i < 3; ++i) {
        int idx = i * 256 + t;
        if (idx < 720) *(f32x4*)(lds + YS_B + idx * 16) = f32x4{0.f, 0.f, 0.f, 0.f};
    }
    if (stg) write_windows(wptr, ldv);
    __syncthreads();

    for (int pair = 0; pair < 8; ++pair) {
        if (pair < 7 && stg) {
            const float* gp = x + (base_s + (size_t)(pair + 1) * 2 + ssp) * 3072 + goff;
#pragma unroll
            for (int i = 0; i < 8; ++i) ldv[i] = *(const float4*)(gp + 4 * i);
        }
        f16* ysp = YS + pair * 720;
#pragma unroll
        for (int ti = 0; ti < 3; ++ti) {
            if (ti < ntiles) {
                const unsigned char* pA = lds + rowbase[ti];
                f32x4 acc = {0.f, 0.f, 0.f, 0.f};
#pragma unroll
                for (int st = 0; st < 6; ++st) {
                    f16x8 af = *(const f16x8*)(pA + seg2off[st]);
                    acc = __builtin_amdgcn_mfma_f32_16x16x32_f16(af, wcf[st], acc, 0, 0, 0);
                }
                if (lr < 4) {
#pragma unroll
                    for (int r = 0; r < 4; ++r) {
                        int off = coff[ti][r];
                        if (off >= 0) {
                            float y = acc[r];
                            ysp[off] = (f16)(y * y);
                        }
                    }
                }
            }
        }
        __syncthreads();                       // readers of WIN done, YS visible
        if (pair < 7) {
            if (stg) write_windows(wptr, ldv);
            __syncthreads();                   // WIN ready for next pair
        }
    }

    // ---------------- fc1: M=16 samples, N=64 (wave w -> ntile w), K=352 ----------------
    {
        f32x4 a1 = {0.f, 0.f, 0.f, 0.f};
        const int n = w * 16 + lr;
#pragma unroll
        for (int st = 0; st < 11; ++st) {
            f16x8 av = *(const f16x8*)(YS + lr * 360 + st * 32 + g * 8);
            f16x8 bh = *(const f16x8*)(w1t +          n * 352 + st * 32 + g * 8);
            f16x8 bl = *(const f16x8*)(w1t + 22528 +  n * 352 + st * 32 + g * 8);
            a1 = __builtin_amdgcn_mfma_f32_16x16x32_f16(av, bh, a1, 0, 0, 0);
            a1 = __builtin_amdgcn_mfma_f32_16x16x32_f16(av, bl, a1, 0, 0, 0);
        }
        float bias = fc1b[n];
#pragma unroll
        for (int r = 0; r < 4; ++r) {
            int s = g * 4 + r;
            float h = a1[r] + bias;
            HSQ[s * 65 + n] = h * h;
        }
    }
    __syncthreads();

    // ---------------- fc2: 160 outputs ----------------
    if (t < 160) {
        int sj = t / 10, j = t - sj * 10;
        float a = fc2b[j];
        const float* wr = fc2w + j * 64;
        const float* hv = &HSQ[sj * 65];
#pragma unroll
        for (int i = 0; i < 64; ++i) a += wr[i] * hv[i];
        out[(base_s + sj) * 10 + j] = a;
    }
}

extern "C" void kernel_launch(void* const* d_in, const int* in_sizes, int n_in,
                              void* d_out, int out_size, void* d_ws, size_t ws_size,
                              hipStream_t stream) {
    const float* x    = (const float*)d_in[0];
    const float* cw   = (const float*)d_in[1];
    const float* fc1w = (const float*)d_in[2];
    const float* fc1b = (const float*)d_in[3];
    const float* fc2w = (const float*)d_in[4];
    const float* fc2b = (const float*)d_in[5];
    float* out = (float*)d_out;

    f16* w1t = (f16*)d_ws;                 // 45056 f16 = 90112 B
    f16* wct = w1t + 45056;                // 6144 f16  = 12288 B

    hipLaunchKernelGGL(prep_weights, dim3(200), dim3(256), 0, stream, cw, fc1w, w1t, wct);

    const int B = in_sizes[0] / 3072;      // 16384
    hipLaunchKernelGGL(convnet_mfma, dim3(B / 16), dim3(256), 0, stream,
                       x, w1t, wct, fc1b, fc2w, fc2b, out);
}

// Round 8
// 46.427 us; speedup vs baseline: 1.1254x; 1.1254x over previous
//
#include <hip/hip_runtime.h>
#include <string.h>

// Fused ConvNet, single dispatch: conv7x7 s3 (3->4) -> ^2 -> FC 324->64 -> ^2 -> FC 64->10
// conv + fc1 on v_mfma_f32_16x16x32_f16. x staged as fp16 windows in LDS
// (window-major: one aligned ds_read_b128 per A-fragment). Conv weights fp16
// (cvt in-kernel); fc1 weights fp16 hi/lo built on the fly from fc1w (its
// K-order is exactly oc*81+p = fc1w column order). No prep kernel, no ws.
// Block = 256 thr (4 waves) = 16 samples, 8 sample-pairs, 2 barriers/pair.
// LDS 39168 B -> 4 blocks/CU.
// Round 8 fix: ntiles formula (wave u=1 was dropping tile 9 -> stale YS rows).

typedef _Float16 f16;
typedef f16 f16x8 __attribute__((ext_vector_type(8)));
typedef __fp16 fp16x2 __attribute__((ext_vector_type(2)));
typedef float f32x4 __attribute__((ext_vector_type(4)));

#define YS_B   27648                   // byte offset of YS region
#define LDS_B  (27648 + 11520)         // WIN pair (27648 B) + YS[16][360]h

__device__ __forceinline__ unsigned pack_rtz(float a, float b) {
    fp16x2 h = __builtin_amdgcn_cvt_pkrtz(a, b);
    unsigned u; memcpy(&u, &h, 4); return u;
}

// pack one row (8 float4 = 32 cols) and write its 9 windows of 8 halves
__device__ __forceinline__ void write_windows(f16* wptr, const float4 ldv[8]) {
    unsigned h[16];
#pragma unroll
    for (int i = 0; i < 8; ++i) {
        h[2*i]   = pack_rtz(ldv[i].x, ldv[i].y);
        h[2*i+1] = pack_rtz(ldv[i].z, ldv[i].w);
    }
#pragma unroll
    for (int ow = 0; ow < 9; ow += 2) {          // 3*ow even: direct
        int d = (3 * ow) >> 1;
        uint4 v; v.x = h[d]; v.y = h[d+1]; v.z = h[d+2]; v.w = h[d+3];
        *reinterpret_cast<uint4*>(wptr + ow * 8) = v;
    }
#pragma unroll
    for (int ow = 1; ow < 9; ow += 2) {          // 3*ow odd: shift one half
        int d = (3 * ow) >> 1;
        uint4 v;
        v.x = __builtin_amdgcn_alignbit(h[d+1], h[d],   16);
        v.y = __builtin_amdgcn_alignbit(h[d+2], h[d+1], 16);
        v.z = __builtin_amdgcn_alignbit(h[d+3], h[d+2], 16);
        v.w = __builtin_amdgcn_alignbit(h[d+4], h[d+3], 16);
        *reinterpret_cast<uint4*>(wptr + ow * 8) = v;
    }
}

// float8 (two float4) -> fp16 hi + lo residual fragments
__device__ __forceinline__ void split_hi_lo(float4 v0, float4 v1, f16x8& bh, f16x8& bl) {
    float v[8] = {v0.x, v0.y, v0.z, v0.w, v1.x, v1.y, v1.z, v1.w};
#pragma unroll
    for (int j = 0; j < 8; ++j) {
        f16 hi = (f16)v[j];
        bh[j] = hi;
        bl[j] = (f16)(v[j] - (float)hi);
    }
}

__global__ __launch_bounds__(256, 4) void convnet_mfma(
    const float* __restrict__ x,
    const float* __restrict__ cw,      // [4][3][7][7]
    const float* __restrict__ fc1w,    // [64][324]
    const float* __restrict__ fc1b,
    const float* __restrict__ fc2w,    // [10][64]
    const float* __restrict__ fc2b,
    float* __restrict__ out)
{
    __shared__ unsigned char lds[LDS_B];
    f16* WINH = (f16*)lds;                         // [2 samples][3][32][9][8] halves
    f16* YS   = (f16*)(lds + YS_B);                // [16][360] halves
    float* HSQ = (float*)lds;                      // overlay on WIN (post-conv)

    const int t    = threadIdx.x;
    const int lane = t & 63;
    const int w    = t >> 6;
    const int g    = lane >> 4;
    const int lr   = lane & 15;
    const size_t base_s = (size_t)blockIdx.x * 16;

    // ---- conv W fragments built in-kernel: lane holds col=lr, k=st*32+g*8..+7 ----
    f16x8 wcf[6];
#pragma unroll
    for (int st = 0; st < 6; ++st) {
        f16x8 v = {0, 0, 0, 0, 0, 0, 0, 0};
        int seg = st * 4 + g;
        if (lr < 4 && seg <= 20) {
            int ci = seg >= 14 ? 2 : (seg >= 7 ? 1 : 0);
            int kh = seg - ci * 7;
            const float* wr = cw + ((lr * 3 + ci) * 7 + kh) * 7;
#pragma unroll
            for (int j = 0; j < 7; ++j) v[j] = (f16)wr[j];
        }
        wcf[st] = v;
    }

    // seg byte offsets (seg = st*4+g, clamped; pad segs have zero weights)
    int seg2off[6];
#pragma unroll
    for (int st = 0; st < 6; ++st) {
        int seg  = st * 4 + g;
        int segc = seg > 20 ? 20 : seg;
        int ci   = segc >= 14 ? 2 : (segc >= 7 ? 1 : 0);
        int kh   = segc - ci * 7;
        seg2off[st] = ci * 4608 + kh * 144;        // bytes: ci*(32*9*16) + kh*(9*16)
    }
    // conv wave id u = 3-w: non-stager (w3 -> u0) gets full tiles.
    // coverage: u0{0,4,8} u1{1,5,9} u2{2,6,10} u3{3,7}  -> all 11 tiles
    const int u = 3 - w;
    const int ntiles = (u == 3) ? 2 : 3;
    int rowbase[3], coff[3][4];
#pragma unroll
    for (int ti = 0; ti < 3; ++ti) {
        int tile = u + ti * 4;
        int tc   = tile > 10 ? 10 : tile;
        int grow = tc * 16 + lr;
        int growc = grow > 161 ? 161 : grow;
        int sp  = growc >= 81;
        int p   = growc - (sp ? 81 : 0);
        int oh  = (p * 57) >> 9;
        int ow  = p - oh * 9;
        rowbase[ti] = sp * 13824 + oh * 432 + ow * 16;   // bytes
#pragma unroll
        for (int r = 0; r < 4; ++r) {
            int gr = tc * 16 + g * 4 + r;
            if (ti < ntiles && gr < 162) {
                int sp2 = gr >= 81;
                int p2  = gr - (sp2 ? 81 : 0);
                coff[ti][r] = sp2 * 360 + lr * 81 + p2;
            } else coff[ti][r] = -1;
        }
    }

    // staging identity: 192 threads own (sample, ci, row)
    const bool stg = t < 192;
    const int ssp  = (t >= 96) ? 1 : 0;
    const int srem = t - ssp * 96;
    const int sci  = srem >> 5;
    const int srow = srem & 31;
    const int goff = sci * 1024 + srow * 32;
    f16* wptr = WINH + ssp * 6912 + sci * 2304 + srow * 72;

    // prologue: load + write pair 0, zero YS (incl. pad tail per sample)
    float4 ldv[8];
    if (stg) {
        const float* gp = x + (base_s + ssp) * 3072 + goff;
#pragma unroll
        for (int i = 0; i < 8; ++i) ldv[i] = *(const float4*)(gp + 4 * i);
    }
#pragma unroll
    for (int i = 0; i < 3; ++i) {
        int idx = i * 256 + t;
        if (idx < 720) *(f32x4*)(lds + YS_B + idx * 16) = f32x4{0.f, 0.f, 0.f, 0.f};
    }
    if (stg) write_windows(wptr, ldv);
    __syncthreads();

    for (int pair = 0; pair < 8; ++pair) {
        if (pair < 7 && stg) {
            const float* gp = x + (base_s + (size_t)(pair + 1) * 2 + ssp) * 3072 + goff;
#pragma unroll
            for (int i = 0; i < 8; ++i) ldv[i] = *(const float4*)(gp + 4 * i);
        }
        f16* ysp = YS + pair * 720;
        __builtin_amdgcn_s_setprio(1);
#pragma unroll
        for (int ti = 0; ti < 3; ++ti) {
            if (ti < ntiles) {
                const unsigned char* pA = lds + rowbase[ti];
                f32x4 acc = {0.f, 0.f, 0.f, 0.f};
#pragma unroll
                for (int st = 0; st < 6; ++st) {
                    f16x8 af = *(const f16x8*)(pA + seg2off[st]);
                    acc = __builtin_amdgcn_mfma_f32_16x16x32_f16(af, wcf[st], acc, 0, 0, 0);
                }
                if (lr < 4) {
#pragma unroll
                    for (int r = 0; r < 4; ++r) {
                        int off = coff[ti][r];
                        if (off >= 0) {
                            float y = acc[r];
                            ysp[off] = (f16)(y * y);
                        }
                    }
                }
            }
        }
        __builtin_amdgcn_s_setprio(0);
        __syncthreads();                       // WIN reads done, YS visible
        if (pair < 7) {
            if (stg) write_windows(wptr, ldv);
            __syncthreads();                   // WIN ready for next pair
        }
    }

    // ---------------- fc1: M=16 samples, N=64; B from fc1w (hi/lo on the fly) ----
    {
        f32x4 a1 = {0.f, 0.f, 0.f, 0.f};
        const int n = w * 16 + lr;
        const float* w1r = fc1w + n * 324;
        __builtin_amdgcn_s_setprio(1);
#pragma unroll
        for (int st = 0; st < 10; ++st) {
            f16x8 av = *(const f16x8*)(YS + lr * 360 + st * 32 + g * 8);
            float4 v0 = *(const float4*)(w1r + st * 32 + g * 8);
            float4 v1 = *(const float4*)(w1r + st * 32 + g * 8 + 4);
            f16x8 bh, bl;
            split_hi_lo(v0, v1, bh, bl);
            a1 = __builtin_amdgcn_mfma_f32_16x16x32_f16(av, bh, a1, 0, 0, 0);
            a1 = __builtin_amdgcn_mfma_f32_16x16x32_f16(av, bl, a1, 0, 0, 0);
        }
        {   // st = 10: k = 320..351, only 320..323 carry data (g==0, j<4)
            f16x8 av = *(const f16x8*)(YS + lr * 360 + 320 + g * 8);
            f16x8 bh = {0,0,0,0,0,0,0,0}, bl = {0,0,0,0,0,0,0,0};
            if (g == 0) {
                float4 v0 = *(const float4*)(w1r + 320);
                float v[4] = {v0.x, v0.y, v0.z, v0.w};
#pragma unroll
                for (int j = 0; j < 4; ++j) {
                    f16 hi = (f16)v[j];
                    bh[j] = hi;
                    bl[j] = (f16)(v[j] - (float)hi);
                }
            }
            a1 = __builtin_amdgcn_mfma_f32_16x16x32_f16(av, bh, a1, 0, 0, 0);
            a1 = __builtin_amdgcn_mfma_f32_16x16x32_f16(av, bl, a1, 0, 0, 0);
        }
        __builtin_amdgcn_s_setprio(0);
        float bias = fc1b[n];
#pragma unroll
        for (int r = 0; r < 4; ++r) {
            int s = g * 4 + r;
            float h = a1[r] + bias;
            HSQ[s * 65 + n] = h * h;           // overlays WIN (conv done)
        }
    }
    __syncthreads();

    // ---------------- fc2: 160 outputs ----------------
    if (t < 160) {
        int sj = t / 10, j = t - sj * 10;
        float a = fc2b[j];
        const float* wr = fc2w + j * 64;
        const float* hv = &HSQ[sj * 65];
#pragma unroll
        for (int i = 0; i < 64; ++i) a += wr[i] * hv[i];
        out[(base_s + sj) * 10 + j] = a;
    }
}

extern "C" void kernel_launch(void* const* d_in, const int* in_sizes, int n_in,
                              void* d_out, int out_size, void* d_ws, size_t ws_size,
                              hipStream_t stream) {
    const float* x    = (const float*)d_in[0];
    const float* cw   = (const float*)d_in[1];
    const float* fc1w = (const float*)d_in[2];
    const float* fc1b = (const float*)d_in[3];
    const float* fc2w = (const float*)d_in[4];
    const float* fc2b = (const float*)d_in[5];
    float* out = (float*)d_out;

    const int B = in_sizes[0] / 3072;      // 16384
    hipLaunchKernelGGL(convnet_mfma, dim3(B / 16), dim3(256), 0, stream,
                       x, cw, fc1w, fc1b, fc2w, fc2b, out);
}

// Round 9
// 45.505 us; speedup vs baseline: 1.1482x; 1.0203x over previous
//
#include <hip/hip_runtime.h>
#include <string.h>

// Fused ConvNet, single dispatch: conv7x7 s3 (3->4) -> ^2 -> FC 324->64 -> ^2 -> FC 64->10
// conv + fc1 on v_mfma_f32_16x16x32_f16. x staged as fp16 windows in LDS
// (window-major: one aligned ds_read_b128 per A-fragment).
// Round 9: 1-sample steps (16 steps) -> LDS 25344 B -> 6 blocks/CU (24 waves).
// Staging in half-rows: 192 threads x 5 float4, each writes 4-5 window b128s.
// Conv weights fp16 (in-kernel cvt); fc1 weights hi/lo fp16 from fc1w on the fly.

typedef _Float16 f16;
typedef f16 f16x8 __attribute__((ext_vector_type(8)));
typedef __fp16 fp16x2 __attribute__((ext_vector_type(2)));
typedef float f32x4 __attribute__((ext_vector_type(4)));

#define YS_B   13824                   // byte offset of YS region (= WIN size)
#define LDS_B  (13824 + 11520)         // WIN[3][32][9][8]h + YS[16][360]h = 25344

__device__ __forceinline__ unsigned pack_rtz(float a, float b) {
    fp16x2 h = __builtin_amdgcn_cvt_pkrtz(a, b);
    unsigned u; memcpy(&u, &h, 4); return u;
}

// stage one half-row: pack 5 float4 (10 dwords) and write 4-5 windows of 8 halves
// half 0: dwords 0..9  (cols 0..19),  windows ow = {0,1,2,3,4} at local d {0,1,3,4,6}
// half 1: dwords 6..15 (cols 12..31), windows ow = {5,6,7,8}   at local d {1,3,4,6}
__device__ __forceinline__ void write_half(f16* wptr, const float4 ldv[5], int half) {
    unsigned h[10];
#pragma unroll
    for (int i = 0; i < 5; ++i) {
        h[2*i]   = pack_rtz(ldv[i].x, ldv[i].y);
        h[2*i+1] = pack_rtz(ldv[i].z, ldv[i].w);
    }
    const int owb = half * 4;
    if (!half) {                                  // ow 0 (direct @0)
        uint4 v; v.x = h[0]; v.y = h[1]; v.z = h[2]; v.w = h[3];
        *reinterpret_cast<uint4*>(wptr) = v;
    }
    {                                             // ow owb+1 (align @1)
        uint4 v;
        v.x = __builtin_amdgcn_alignbit(h[2], h[1], 16);
        v.y = __builtin_amdgcn_alignbit(h[3], h[2], 16);
        v.z = __builtin_amdgcn_alignbit(h[4], h[3], 16);
        v.w = __builtin_amdgcn_alignbit(h[5], h[4], 16);
        *reinterpret_cast<uint4*>(wptr + (owb + 1) * 8) = v;
    }
    {                                             // ow owb+2 (direct @3)
        uint4 v; v.x = h[3]; v.y = h[4]; v.z = h[5]; v.w = h[6];
        *reinterpret_cast<uint4*>(wptr + (owb + 2) * 8) = v;
    }
    {                                             // ow owb+3 (align @4)
        uint4 v;
        v.x = __builtin_amdgcn_alignbit(h[5], h[4], 16);
        v.y = __builtin_amdgcn_alignbit(h[6], h[5], 16);
        v.z = __builtin_amdgcn_alignbit(h[7], h[6], 16);
        v.w = __builtin_amdgcn_alignbit(h[8], h[7], 16);
        *reinterpret_cast<uint4*>(wptr + (owb + 3) * 8) = v;
    }
    {                                             // ow owb+4 (direct @6)
        uint4 v; v.x = h[6]; v.y = h[7]; v.z = h[8]; v.w = h[9];
        *reinterpret_cast<uint4*>(wptr + (owb + 4) * 8) = v;
    }
}

__global__ __launch_bounds__(256, 6) void convnet_mfma(
    const float* __restrict__ x,
    const float* __restrict__ cw,      // [4][3][7][7]
    const float* __restrict__ fc1w,    // [64][324]
    const float* __restrict__ fc1b,
    const float* __restrict__ fc2w,    // [10][64]
    const float* __restrict__ fc2b,
    float* __restrict__ out)
{
    __shared__ unsigned char lds[LDS_B];
    f16* WINH = (f16*)lds;                         // [3][32][9][8] halves (one sample)
    f16* YS   = (f16*)(lds + YS_B);                // [16][360] halves
    float* HSQ = (float*)lds;                      // overlay on WIN (post-conv)

    const int t    = threadIdx.x;
    const int lane = t & 63;
    const int w    = t >> 6;
    const int g    = lane >> 4;
    const int lr   = lane & 15;
    const size_t base_s = (size_t)blockIdx.x * 16;

    // ---- conv W fragments: lane holds col=lr, k = st*32 + g*8 .. +7 ----
    f16x8 wcf[6];
#pragma unroll
    for (int st = 0; st < 6; ++st) {
        f16x8 v = {0, 0, 0, 0, 0, 0, 0, 0};
        int seg = st * 4 + g;
        if (lr < 4 && seg <= 20) {
            int ci = seg >= 14 ? 2 : (seg >= 7 ? 1 : 0);
            int kh = seg - ci * 7;
            const float* wr = cw + ((lr * 3 + ci) * 7 + kh) * 7;
#pragma unroll
            for (int j = 0; j < 7; ++j) v[j] = (f16)wr[j];
        }
        wcf[st] = v;
    }

    // seg byte offsets (seg = st*4+g, clamped; pad segs have zero weights)
    int seg2off[6];
#pragma unroll
    for (int st = 0; st < 6; ++st) {
        int seg  = st * 4 + g;
        int segc = seg > 20 ? 20 : seg;
        int ci   = segc >= 14 ? 2 : (segc >= 7 ? 1 : 0);
        int kh   = segc - ci * 7;
        seg2off[st] = ci * 4608 + kh * 144;        // bytes: ci*(32*9*16) + kh*(9*16)
    }

    // conv tiles (6 of 16 rows over 81 positions): wave u=3-w gets {u, u+4}
    // u0(w3): {0,4}  u1(w2): {1,5}  u2(w1): {2}  u3(w0): {3}
    const int u = 3 - w;
    const int ntiles = (u < 2) ? 2 : 1;
    int rowbase[2], pbase[2];
#pragma unroll
    for (int ti = 0; ti < 2; ++ti) {
        int tile = u + ti * 4;
        int tc   = tile > 5 ? 5 : tile;
        int grow = tc * 16 + lr;
        int p    = grow > 80 ? 80 : grow;
        int oh   = (p * 57) >> 9;
        int ow   = p - oh * 9;
        rowbase[ti] = oh * 432 + ow * 16;          // bytes
        pbase[ti]   = tc * 16 + g * 4;             // C rows p = pbase + r
    }

    // staging identity: 192 threads = (ci,row) x half
    const bool stg  = t < 192;
    const int  r_   = t >> 1;                      // 0..95
    const int  half = t & 1;
    const int  sci  = r_ >> 5;
    const int  srow = r_ & 31;
    const int  goff = sci * 1024 + srow * 32 + (half ? 12 : 0);
    f16* wptr = WINH + sci * 2304 + srow * 72;

    // prologue: load + stage sample 0, zero YS
    float4 ldv[5];
    if (stg) {
        const float* gp = x + base_s * 3072 + goff;
#pragma unroll
        for (int i = 0; i < 5; ++i) ldv[i] = *(const float4*)(gp + 4 * i);
    }
#pragma unroll
    for (int i = 0; i < 3; ++i) {
        int idx = i * 256 + t;
        if (idx < 720) *(f32x4*)(lds + YS_B + idx * 16) = f32x4{0.f, 0.f, 0.f, 0.f};
    }
    if (stg) write_half(wptr, ldv, half);
    __syncthreads();

    for (int s = 0; s < 16; ++s) {
        if (s < 15 && stg) {
            const float* gp = x + (base_s + s + 1) * 3072 + goff;
#pragma unroll
            for (int i = 0; i < 5; ++i) ldv[i] = *(const float4*)(gp + 4 * i);
        }
        f16* ysp = YS + s * 360;
        __builtin_amdgcn_s_setprio(1);
#pragma unroll
        for (int ti = 0; ti < 2; ++ti) {
            if (ti < ntiles) {
                const unsigned char* pA = lds + rowbase[ti];
                f32x4 acc = {0.f, 0.f, 0.f, 0.f};
#pragma unroll
                for (int st = 0; st < 6; ++st) {
                    f16x8 af = *(const f16x8*)(pA + seg2off[st]);
                    acc = __builtin_amdgcn_mfma_f32_16x16x32_f16(af, wcf[st], acc, 0, 0, 0);
                }
                if (lr < 4) {
#pragma unroll
                    for (int r = 0; r < 4; ++r) {
                        int p = pbase[ti] + r;
                        if (p < 81) {
                            float y = acc[r];
                            ysp[lr * 81 + p] = (f16)(y * y);
                        }
                    }
                }
            }
        }
        __builtin_amdgcn_s_setprio(0);
        __syncthreads();                       // WIN reads done, YS visible
        if (s < 15) {
            if (stg) write_half(wptr, ldv, half);
            __syncthreads();                   // WIN ready for next sample
        }
    }

    // ---------------- fc1: M=16 samples, N=64; B from fc1w (hi/lo on the fly) ----
    {
        f32x4 a1 = {0.f, 0.f, 0.f, 0.f};
        const int n = w * 16 + lr;
        const float* w1r = fc1w + n * 324;
        __builtin_amdgcn_s_setprio(1);
#pragma unroll
        for (int st = 0; st < 10; ++st) {
            f16x8 av = *(const f16x8*)(YS + lr * 360 + st * 32 + g * 8);
            float4 v0 = *(const float4*)(w1r + st * 32 + g * 8);
            float4 v1 = *(const float4*)(w1r + st * 32 + g * 8 + 4);
            float vv[8] = {v0.x, v0.y, v0.z, v0.w, v1.x, v1.y, v1.z, v1.w};
            f16x8 bh, bl;
#pragma unroll
            for (int j = 0; j < 8; ++j) {
                f16 hi = (f16)vv[j];
                bh[j] = hi;
                bl[j] = (f16)(vv[j] - (float)hi);
            }
            a1 = __builtin_amdgcn_mfma_f32_16x16x32_f16(av, bh, a1, 0, 0, 0);
            a1 = __builtin_amdgcn_mfma_f32_16x16x32_f16(av, bl, a1, 0, 0, 0);
        }
        {   // st = 10: k = 320..351, only 320..323 carry data (g==0, j<4)
            f16x8 av = *(const f16x8*)(YS + lr * 360 + 320 + g * 8);
            f16x8 bh = {0,0,0,0,0,0,0,0}, bl = {0,0,0,0,0,0,0,0};
            if (g == 0) {
                float4 v0 = *(const float4*)(w1r + 320);
                float vv[4] = {v0.x, v0.y, v0.z, v0.w};
#pragma unroll
                for (int j = 0; j < 4; ++j) {
                    f16 hi = (f16)vv[j];
                    bh[j] = hi;
                    bl[j] = (f16)(vv[j] - (float)hi);
                }
            }
            a1 = __builtin_amdgcn_mfma_f32_16x16x32_f16(av, bh, a1, 0, 0, 0);
            a1 = __builtin_amdgcn_mfma_f32_16x16x32_f16(av, bl, a1, 0, 0, 0);
        }
        __builtin_amdgcn_s_setprio(0);
        float bias = fc1b[n];
#pragma unroll
        for (int r = 0; r < 4; ++r) {
            int s = g * 4 + r;
            float h = a1[r] + bias;
            HSQ[s * 65 + n] = h * h;           // overlays WIN (conv done)
        }
    }
    __syncthreads();

    // ---------------- fc2: 160 outputs ----------------
    if (t < 160) {
        int sj = t / 10, j = t - sj * 10;
        float a = fc2b[j];
        const float* wr = fc2w + j * 64;
        const float* hv = &HSQ[sj * 65];
#pragma unroll
        for (int i = 0; i < 64; ++i) a += wr[i] * hv[i];
        out[(base_s + sj) * 10 + j] = a;
    }
}

extern "C" void kernel_launch(void* const* d_in, const int* in_sizes, int n_in,
                              void* d_out, int out_size, void* d_ws, size_t ws_size,
                              hipStream_t stream) {
    const float* x    = (const float*)d_in[0];
    const float* cw   = (const float*)d_in[1];
    const float* fc1w = (const float*)d_in[2];
    const float* fc1b = (const float*)d_in[3];
    const float* fc2w = (const float*)d_in[4];
    const float* fc2b = (const float*)d_in[5];
    float* out = (float*)d_out;

    const int B = in_sizes[0] / 3072;      // 16384
    hipLaunchKernelGGL(convnet_mfma, dim3(B / 16), dim3(256), 0, stream,
                       x, cw, fc1w, fc1b, fc2w, fc2b, out);
}